// Round 16
// baseline (874.023 us; speedup 1.0000x reference)
//
#include <hip/hip_runtime.h>
#include <math.h>

// ---------------- problem constants ----------------
#define BBATCH 4096
#define LLEN   4096
#define DDIM   1024
#define CCLS   64
#define NSUP   8192
#define NTOT   12288            // NSUP + BBATCH
#define FEPS   1e-12f
#define KCHUNK 48               // NTOT / 256 support chunks
#define KCAND  (KCHUNK*6)       // 288 candidates per row

// scalar accumulator slots
#define SC_SUMP  0
#define SC_SUME  1
#define SC_SUMWC 2
#define SC_TSAL  3
#define SC_L2NUM 4
#define SC_L3NUM 5

typedef _Float16 half4_t __attribute__((ext_vector_type(4)));
typedef _Float16 half8_t __attribute__((ext_vector_type(8)));
typedef float    f32x4   __attribute__((ext_vector_type(4)));
typedef float    f32x16  __attribute__((ext_vector_type(16)));

// ---------------- workspace layout (float offsets) ----------------
static const size_t OFF_FEATS  = 0;                                    // B*D
static const size_t OFF_FEATP1 = OFF_FEATS  + (size_t)BBATCH*DDIM;     // B*D
static const size_t OFF_WFTH   = OFF_FEATP1 + (size_t)BBATCH*DDIM;     // D*L halves
static const size_t OFF_WFTL   = OFF_WFTH   + (size_t)DDIM*LLEN/2;     // D*L halves
static const size_t OFF_PROBS  = OFF_WFTL   + (size_t)DDIM*LLEN/2;     // B*C
static const size_t OFF_LOGP   = OFF_PROBS  + (size_t)BBATCH*CCLS;     // B*C
static const size_t OFF_FNORM  = OFF_LOGP   + (size_t)BBATCH*CCLS;     // B
static const size_t OFF_SNORM  = OFF_FNORM  + BBATCH;                  // N
static const size_t OFF_PMAX   = OFF_SNORM  + NSUP;                    // B
static const size_t OFF_EROW   = OFF_PMAX   + BBATCH;                  // B
static const size_t OFF_WC     = OFF_EROW   + BBATCH;                  // B
static const size_t OFF_PRED   = OFF_WC     + BBATCH;                  // B (int)
static const size_t OFF_RB     = OFF_PRED   + BBATCH;                  // B
static const size_t OFF_SNM    = OFF_RB     + BBATCH;                  // NTOT
static const size_t OFF_PROTOT = OFF_SNM    + NTOT;                    // C*D
static const size_t OFF_CVAL   = OFF_PROTOT + (size_t)CCLS*DDIM;       // B*KCAND
static const size_t OFF_CIDX   = OFF_CVAL   + (size_t)BBATCH*KCAND;    // B*KCAND (int)
static const size_t OFF_ZERO   = OFF_CIDX   + (size_t)BBATCH*KCAND;    // zeroed region:
static const size_t OFF_MACC   = OFF_ZERO;                             // C
static const size_t OFF_PMACC  = OFF_MACC   + CCLS;                    // C
static const size_t OFF_COLS   = OFF_PMACC  + CCLS;                    // C
static const size_t OFF_SCAL   = OFF_COLS   + CCLS;                    // 32
static const size_t OFF_PROTUN = OFF_SCAL   + 32;                      // D*C
static const size_t OFF_ZEND   = OFF_PROTUN + (size_t)DDIM*CCLS;       // end zeroed
static const size_t OFF_HT     = OFF_ZEND;                             // 32*NTOT*32 halves (25.2MB)
static const size_t WS_END     = OFF_HT + (size_t)32*NTOT*32/2;

// ---------------- helpers ----------------
__device__ __forceinline__ float waveSum(float v){
  #pragma unroll
  for (int o = 32; o > 0; o >>= 1) v += __shfl_xor(v, o);
  return v;
}
__device__ __forceinline__ float waveMax(float v){
  #pragma unroll
  for (int o = 32; o > 0; o >>= 1) v = fmaxf(v, __shfl_xor(v, o));
  return v;
}
__device__ __forceinline__ float blockSum256(float v, float* sh4){
  v = waveSum(v);
  if ((threadIdx.x & 63) == 0) sh4[threadIdx.x >> 6] = v;
  __syncthreads();
  float r = sh4[0] + sh4[1] + sh4[2] + sh4[3];
  __syncthreads();
  return r;
}
// branchless top-6 insertion (strict > keeps earlier-inserted on ties)
__device__ __forceinline__ void top6_insert(float* v, int* ix, float s, int si){
  bool c0=s>v[0],c1=s>v[1],c2=s>v[2],c3=s>v[3],c4=s>v[4],c5=s>v[5];
  v[5]=c5?(c4?v[4]:s):v[5]; ix[5]=c5?(c4?ix[4]:si):ix[5];
  v[4]=c4?(c3?v[3]:s):v[4]; ix[4]=c4?(c3?ix[3]:si):ix[4];
  v[3]=c3?(c2?v[2]:s):v[3]; ix[3]=c3?(c2?ix[2]:si):ix[3];
  v[2]=c2?(c1?v[1]:s):v[2]; ix[2]=c2?(c1?ix[1]:si):ix[2];
  v[1]=c1?(c0?v[0]:s):v[1]; ix[1]=c1?(c0?ix[0]:si):ix[1];
  v[0]=c0?s:v[0];           ix[0]=c0?si:ix[0];
}
// fp32 -> f16 hi + f16 lo (residual)
__device__ __forceinline__ void split4(const float4 v, half4_t* h, half4_t* l){
  half4_t hh, ll;
  hh[0] = (_Float16)v.x; hh[1] = (_Float16)v.y; hh[2] = (_Float16)v.z; hh[3] = (_Float16)v.w;
  ll[0] = (_Float16)(v.x - (float)hh[0]);
  ll[1] = (_Float16)(v.y - (float)hh[1]);
  ll[2] = (_Float16)(v.z - (float)hh[2]);
  ll[3] = (_Float16)(v.w - (float)hh[3]);
  *h = hh; *l = ll;
}
// ht tiled layout: element (row, d) -> kt=d>>5 tile, row-major 32-half rows,
// 8-half slots XOR-swizzled by ((row>>3)&3) for conflict-free ds_read_b128.
__device__ __forceinline__ size_t ht_off(int row, int d){
  int kt = d >> 5;
  int slot = ((d >> 3) & 3) ^ ((row >> 3) & 3);
  return (size_t)kt * (NTOT*32) + (size_t)row * 32 + slot*8 + (d & 7);
}

// ---------------- 1. per-row input-energy entropy ----------------
__global__ __launch_bounds__(256)
void k_entropy(const float* __restrict__ x, float* __restrict__ e_row,
               float* __restrict__ scal){
  __shared__ __align__(16) float lx[LLEN];
  __shared__ float sh4[4];
  int row = blockIdx.x, t = threadIdx.x;
  const float4* xr = (const float4*)(x + (size_t)row * LLEN);
  float s = 0.f;
  #pragma unroll
  for (int i = 0; i < 4; ++i){
    float4 v = xr[t + 256*i];
    ((float4*)lx)[t + 256*i] = v;
    s += v.x*v.x + v.y*v.y + v.z*v.z + v.w*v.w;
  }
  s = blockSum256(s, sh4);
  float inv = 1.0f / fmaxf(s, FEPS);
  float ent = 0.f;
  #pragma unroll
  for (int i = 0; i < 4; ++i){
    float4 v = ((float4*)lx)[t + 256*i];
    float p;
    p = v.x*v.x*inv; ent -= p * logf(p + 1e-30f);
    p = v.y*v.y*inv; ent -= p * logf(p + 1e-30f);
    p = v.z*v.z*inv; ent -= p * logf(p + 1e-30f);
    p = v.w*v.w*inv; ent -= p * logf(p + 1e-30f);
  }
  ent = blockSum256(ent, sh4);
  if (t == 0){ e_row[row] = ent; atomicAdd(&scal[SC_SUME], ent); }
}

// ---------------- 2a. Wf transpose + f16 split ----------------
__global__ __launch_bounds__(256)
void k_wft(const float* __restrict__ Wf, unsigned short* __restrict__ WftH,
           unsigned short* __restrict__ WftL){
  __shared__ __align__(16) float ld[64*68];
  int t = threadIdx.x;
  int d0 = blockIdx.x * 64;
  int l0 = blockIdx.y * 64;
  #pragma unroll
  for (int i = 0; i < 4; ++i){
    int flat = t + 256*i;
    int l = flat >> 4, d4 = (flat & 15) * 4;
    *(float4*)&ld[l*68 + d4] = *(const float4*)(Wf + (size_t)(l0+l)*DDIM + d0 + d4);
  }
  __syncthreads();
  #pragma unroll
  for (int i = 0; i < 4; ++i){
    int flat = t + 256*i;
    int d = flat >> 4, l4 = (flat & 15) * 4;
    float4 v = make_float4(ld[(l4+0)*68 + d], ld[(l4+1)*68 + d],
                           ld[(l4+2)*68 + d], ld[(l4+3)*68 + d]);
    half4_t h, l;
    split4(v, &h, &l);
    *(half4_t*)(WftH + (size_t)(d0+d)*LLEN + l0 + l4) = h;
    *(half4_t*)(WftL + (size_t)(d0+d)*LLEN + l0 + l4) = l;
  }
}

// ---------------- 2b. feats = x @ Wf via f16x3 MFMA (32x32x16), K-split x2 ----------------
// A (x fp32) staged via global_load_lds with source granule-XOR pre-swizzle;
// f32 -> h/l split in regs on LDS read-back. B (Wft h/l) gload as before.
// LDS per buffer (halves): Af32 [0,8192), Bh [8192,12288), Bl [12288,16384).
__global__ __launch_bounds__(256)
void k_feats_mfma(const float* __restrict__ X, const unsigned short* __restrict__ WftHu,
                  const unsigned short* __restrict__ WftLu, float* __restrict__ featp){
  __shared__ __align__(16) _Float16 lds[2*16384];   // 64KB
  int t = threadIdx.x;
  int n0 = blockIdx.x * 128;
  int m0 = blockIdx.y * 128;
  int kz = blockIdx.z;
  int w = t >> 6, lane = t & 63;
  int wr = w >> 1, wc = w & 1;
  int l31 = lane & 31, hi = lane >> 5;
  const _Float16* Bgh = (const _Float16*)WftHu + (size_t)n0*LLEN;
  const _Float16* Bgl = (const _Float16*)WftLu + (size_t)n0*LLEN;
  const size_t glRowB = (size_t)(lane >> 2)*LLEN;
  int arow = lane >> 3;
  int agr  = (lane & 7) ^ (arow & 7);
  f32x16 acc[2][2];
  #pragma unroll
  for (int i=0;i<2;++i){
    #pragma unroll
    for (int j=0;j<2;++j) acc[i][j] = (f32x16)(0.f);
  }
  const int kstart = kz*2048;

  #define STAGE_AB(bufi, k0c) do {                                                 \
    _Float16* Lb = lds + (bufi)*16384;                                             \
    _Pragma("unroll")                                                              \
    for (int g = 0; g < 4; ++g){                                                   \
      const float* asrc = X + (size_t)(m0 + w*32 + g*8 + arow)*LLEN + (k0c) + 4*agr;\
      __builtin_amdgcn_global_load_lds(                                            \
        (const __attribute__((address_space(1))) void*)asrc,                       \
        (__attribute__((address_space(3))) void*)(Lb + (w*32 + g*8)*64), 16,0,0);  \
    }                                                                              \
    _Pragma("unroll")                                                              \
    for (int s2 = 0; s2 < 2; ++s2){                                                \
      int blk = s2*4 + w;                                                          \
      int csrc = (lane & 3) ^ ((blk*2 + (lane >> 5)) & 3);                         \
      size_t go = glRowB + (size_t)blk*16*LLEN + (k0c) + (size_t)csrc*8;           \
      __builtin_amdgcn_global_load_lds(                                            \
        (const __attribute__((address_space(1))) void*)(Bgh + go),                 \
        (__attribute__((address_space(3))) void*)(Lb + 8192 + blk*512), 16,0,0);   \
      __builtin_amdgcn_global_load_lds(                                            \
        (const __attribute__((address_space(1))) void*)(Bgl + go),                 \
        (__attribute__((address_space(3))) void*)(Lb + 12288 + blk*512), 16,0,0);  \
    }                                                                              \
  } while(0)

  STAGE_AB(0, kstart);
  for (int it = 0; it < 64; ++it){
    const _Float16* buf = lds + (it&1)*16384;
    __syncthreads();                     // tile it fully landed (vmcnt drained)
    const float* Af = (const float*)buf;
    half8_t ah[2][2], al[2][2];
    #pragma unroll
    for (int p_=0;p_<2;++p_){
      int Ra = wr*64 + p_*32 + l31;
      int rx = Ra & 7;
      #pragma unroll
      for (int kf=0;kf<2;++kf){
        int g0 = kf*4 + hi*2;
        f32x4 v0 = *(const f32x4*)(Af + Ra*32 + 4*((g0  ) ^ rx));
        f32x4 v1 = *(const f32x4*)(Af + Ra*32 + 4*((g0+1) ^ rx));
        half8_t h, l;
        #pragma unroll
        for (int j=0;j<4;++j){
          h[j]   = (_Float16)v0[j]; l[j]   = (_Float16)(v0[j] - (float)h[j]);
          h[4+j] = (_Float16)v1[j]; l[4+j] = (_Float16)(v1[j] - (float)h[4+j]);
        }
        ah[p_][kf] = h; al[p_][kf] = l;
      }
    }
    half8_t bh[2][2], bl[2][2];
    #pragma unroll
    for (int ni=0;ni<2;++ni){
      int Rb = wc*64 + ni*32 + l31;
      int sw = (Rb>>3)&3;
      #pragma unroll
      for (int kf=0;kf<2;++kf){
        int sc = (kf*2 + hi) ^ sw;
        bh[ni][kf] = *(const half8_t*)(buf + 8192  + Rb*32 + sc*8);
        bl[ni][kf] = *(const half8_t*)(buf + 12288 + Rb*32 + sc*8);
      }
    }
    if (it < 63) STAGE_AB((it+1)&1, kstart + (it+1)*32);
    __builtin_amdgcn_s_setprio(1);
    #pragma unroll
    for (int p_=0;p_<2;++p_){
      #pragma unroll
      for (int ni=0;ni<2;++ni){
        #pragma unroll
        for (int kf=0;kf<2;++kf){
          acc[p_][ni] = __builtin_amdgcn_mfma_f32_32x32x16_f16(ah[p_][kf], bh[ni][kf], acc[p_][ni], 0,0,0);
          acc[p_][ni] = __builtin_amdgcn_mfma_f32_32x32x16_f16(ah[p_][kf], bl[ni][kf], acc[p_][ni], 0,0,0);
          acc[p_][ni] = __builtin_amdgcn_mfma_f32_32x32x16_f16(al[p_][kf], bh[ni][kf], acc[p_][ni], 0,0,0);
        }
      }
    }
    __builtin_amdgcn_s_setprio(0);
  }
  #undef STAGE_AB
  // C layout (32x32): col = lane&31, row = (reg&3) + 8*(reg>>2) + 4*(lane>>5)
  float* outp = featp + (size_t)kz * BBATCH * DDIM;
  #pragma unroll
  for (int mi=0;mi<2;++mi){
    #pragma unroll
    for (int ni=0;ni<2;++ni){
      #pragma unroll
      for (int r=0;r<16;++r){
        int row = m0 + wr*64 + mi*32 + (r&3) + 8*(r>>2) + 4*hi;
        int col = n0 + wc*64 + ni*32 + l31;
        outp[(size_t)row*DDIM + col] = acc[mi][ni][r];
      }
    }
  }
}

// ---------------- 3. support row norms + f16-hi tiled pack ----------------
__global__ __launch_bounds__(256)
void k_supnorm(const float* __restrict__ sup, float* __restrict__ snorm,
               _Float16* __restrict__ ht){
  int w = threadIdx.x >> 6, lane = threadIdx.x & 63;
  int row = blockIdx.x*4 + w;
  const float4* rp = (const float4*)(sup + (size_t)row * DDIM);
  float s = 0.f;
  #pragma unroll
  for (int j=0;j<4;++j){
    float4 v = rp[lane + 64*j];
    half4_t h;
    h[0]=(_Float16)v.x; h[1]=(_Float16)v.y; h[2]=(_Float16)v.z; h[3]=(_Float16)v.w;
    int d = (lane + 64*j)*4;
    *(half4_t*)(ht + ht_off(row, d)) = h;
    s += v.x*v.x+v.y*v.y+v.z*v.z+v.w*v.w;
  }
  s = waveSum(s);
  if (lane==0) snorm[row] = sqrtf(s);
}

// ---------------- 4. sum K-split partials -> feats (+f16-hi tiled pack); logits+softmax ----------------
__global__ __launch_bounds__(256)
void k_logits(float* __restrict__ feats, const float* __restrict__ featp1,
              const float* __restrict__ Wc,
              const float* __restrict__ bc, float* __restrict__ probs,
              float* __restrict__ logp, float* __restrict__ pmax,
              int* __restrict__ pred, float* __restrict__ fnorm,
              float* __restrict__ scal,
              _Float16* __restrict__ ht){
  __shared__ __align__(16) float f[DDIM];
  __shared__ float z[CCLS];
  __shared__ float sh4[4];
  int row = blockIdx.x, t = threadIdx.x;
  const float4* fr0 = (const float4*)(feats  + (size_t)row * DDIM);
  const float4* fr1 = (const float4*)(featp1 + (size_t)row * DDIM);
  float ss = 0.f;
  { float4 a = fr0[t], b = fr1[t];
    float4 v = make_float4(a.x+b.x, a.y+b.y, a.z+b.z, a.w+b.w);
    ((float4*)f)[t] = v;
    ((float4*)(feats + (size_t)row*DDIM))[t] = v;
    half4_t h;
    h[0]=(_Float16)v.x; h[1]=(_Float16)v.y; h[2]=(_Float16)v.z; h[3]=(_Float16)v.w;
    *(half4_t*)(ht + ht_off(NSUP + row, t*4)) = h;
    ss += v.x*v.x+v.y*v.y+v.z*v.z+v.w*v.w; }
  ss = blockSum256(ss, sh4);
  if (t==0) fnorm[row] = sqrtf(ss);
  int w = t >> 6, lane = t & 63;
  for (int ci = 0; ci < 16; ++ci){
    int c = w*16 + ci;
    const float4* wc = (const float4*)(Wc + (size_t)c * DDIM);
    float d = 0.f;
    #pragma unroll
    for (int j=0;j<4;++j){
      float4 a = wc[lane + 64*j];
      float4 b = ((float4*)f)[lane + 64*j];
      d += a.x*b.x+a.y*b.y+a.z*b.z+a.w*b.w;
    }
    d = waveSum(d);
    if (lane == 0) z[c] = d + bc[c];
  }
  __syncthreads();
  if (w == 0){
    float zz = z[lane];
    float m = waveMax(zz);
    unsigned long long bal = __ballot(zz == m);
    int am = __ffsll(bal) - 1;
    float ex = expf(zz - m);
    float sv = waveSum(ex);
    probs[(size_t)row*CCLS + lane] = ex / sv;
    logp[(size_t)row*CCLS + lane]  = (zz - m) - logf(sv);
    if (lane == 0){
      float pmv = 1.0f / sv;
      pmax[row] = pmv;
      pred[row] = am;
      atomicAdd(&scal[SC_SUMP], pmv);
    }
  }
}

// ---------------- 5. masks, scale factors ----------------
__global__ __launch_bounds__(256)
void k_mask(const float* __restrict__ e_row, const float* __restrict__ pmax,
            const float* __restrict__ fnorm, const float* __restrict__ snorm,
            const int* __restrict__ pred, float* __restrict__ w_c,
            float* __restrict__ rb, float* __restrict__ snm,
            float* __restrict__ colsum, float* __restrict__ scal){
  int i = blockIdx.x * 256 + threadIdx.x;
  if (i < NSUP) snm[i] = 1.0f / fmaxf(snorm[i], FEPS);
  if (i < BBATCH){
    float me = scal[SC_SUME] * (1.0f/BBATCH);
    float mp = scal[SC_SUMP] * (1.0f/BBATCH);
    float wc = ((e_row[i] < me) && (pmax[i] >= mp)) ? 1.0f : 0.0f;
    w_c[i] = wc;
    float fn = fmaxf(fnorm[i], FEPS);
    rb[i] = 10.0f / fn;
    snm[NSUP + i] = (wc > 0.f) ? (1.0f / fn) : -1.0f;
    atomicAdd(&scal[SC_SUMWC], wc);
    atomicAdd(&colsum[pred[i]], wc);
  }
}

// ---------------- 6. colsum over labels_old ----------------
__global__ __launch_bounds__(256)
void k_colsum_labels(const float* __restrict__ labels, float* __restrict__ colsum){
  int t = threadIdx.x, c = t & 63, sub = t >> 6;
  int r0 = blockIdx.x * 256;
  float s = 0.f;
  for (int i = 0; i < 64; ++i){
    int r = r0 + sub + 4*i;
    s += labels[(size_t)r*CCLS + c];
  }
  __shared__ float loc[4][64];
  loc[sub][c] = s;
  __syncthreads();
  if (sub == 0) atomicAdd(&colsum[c], loc[0][c]+loc[1][c]+loc[2][c]+loc[3][c]);
}

// ---------------- 7. m accumulator ----------------
__global__ __launch_bounds__(256)
void k_m_accum(const float* __restrict__ probs, const float* __restrict__ w_c,
               float* __restrict__ m_acc){
  int t = threadIdx.x, c = t & 63, sub = t >> 6;
  int r0 = blockIdx.x * 64;
  float s = 0.f;
  for (int i = 0; i < 16; ++i){
    int r = r0 + sub + 4*i;
    s += probs[(size_t)r*CCLS + c] * w_c[r];
  }
  __shared__ float loc[4][64];
  loc[sub][c] = s;
  __syncthreads();
  if (sub == 0) atomicAdd(&m_acc[c], loc[0][c]+loc[1][c]+loc[2][c]+loc[3][c]);
}

// ---------------- 8. loss1 pieces ----------------
__global__ __launch_bounds__(256)
void k_loss1(const float* __restrict__ probs, const float* __restrict__ m_acc,
             float* __restrict__ pm_acc, float* __restrict__ scal){
  int t = threadIdx.x, w = t >> 6, lane = t & 63;
  float swc = fmaxf(scal[SC_SUMWC], 1.0f);
  float minv = 1.0f / fmaxf(m_acc[lane] / swc, FEPS);
  float pml = 0.f, tsl = 0.f;
  int r0 = blockIdx.x * 64 + w * 16;
  for (int i = 0; i < 16; ++i){
    int r = r0 + i;
    float pb = probs[(size_t)r*CCLS + lane] * minv;
    float t1 = waveSum(pb);
    float t2 = waveSum(pb*pb);
    tsl += 1.0f - t2/(t1*t1);
    pml += pb/t1;
  }
  atomicAdd(&pm_acc[lane], pml);
  if (lane == 0) atomicAdd(&scal[SC_TSAL], tsl);
}

// ---------------- 9. protos GEMM ----------------
__global__ __launch_bounds__(256)
void k_protos_gemm(const float* __restrict__ sup, const float* __restrict__ feats,
                   const float* __restrict__ labels, const int* __restrict__ pred,
                   const float* __restrict__ w_c, const float* __restrict__ snm,
                   float* __restrict__ protos_un){
  __shared__ __align__(16) float ssx[64*68];
  __shared__ __align__(16) float sl[64*68];
  int t = threadIdx.x;
  int d0 = blockIdx.x * 64;
  int nbase = blockIdx.y * 1536;
  int dg = t & 15, cg = t >> 4;
  float acc[4][4];
  #pragma unroll
  for (int i=0;i<4;++i){
    #pragma unroll
    for (int j=0;j<4;++j) acc[i][j]=0.f;
  }
  for (int n0 = 0; n0 < 1536; n0 += 64){
    __syncthreads();
    #pragma unroll
    for (int i = 0; i < 4; ++i){
      int fidx = t + 256*i;
      int r = fidx >> 4;
      int dc = (fidx & 15) * 4;
      int n = nbase + n0 + r;
      const float* rp = (n < NSUP) ? (sup + (size_t)n*DDIM)
                                   : (feats + (size_t)(n-NSUP)*DDIM);
      *(float4*)&ssx[r*68 + dc] = *(const float4*)(rp + d0 + dc);
    }
    #pragma unroll
    for (int i = 0; i < 4; ++i){
      int fidx = t + 256*i;
      int r = fidx >> 4;
      int cc = (fidx & 15) * 4;
      int n = nbase + n0 + r;
      float sc = snm[n];
      float4 v;
      if (n < NSUP){
        float4 lb = *(const float4*)(labels + (size_t)n*CCLS + cc);
        v.x = lb.x*sc; v.y = lb.y*sc; v.z = lb.z*sc; v.w = lb.w*sc;
      } else {
        int b = n - NSUP;
        float base = w_c[b] * sc;
        int p = pred[b];
        v.x = (p == cc+0) ? base : 0.f;
        v.y = (p == cc+1) ? base : 0.f;
        v.z = (p == cc+2) ? base : 0.f;
        v.w = (p == cc+3) ? base : 0.f;
      }
      *(float4*)&sl[r*68 + cc] = v;
    }
    __syncthreads();
    #pragma unroll 4
    for (int kk = 0; kk < 64; ++kk){
      float4 a = *(float4*)&ssx[kk*68 + 4*dg];
      float4 b = *(float4*)&sl[kk*68 + 4*cg];
      float av[4] = {a.x,a.y,a.z,a.w};
      float bv[4] = {b.x,b.y,b.z,b.w};
      #pragma unroll
      for (int i=0;i<4;++i){
        #pragma unroll
        for (int j=0;j<4;++j) acc[i][j] = fmaf(av[i], bv[j], acc[i][j]);
      }
    }
  }
  #pragma unroll
  for (int i=0;i<4;++i){
    #pragma unroll
    for (int j=0;j<4;++j)
      atomicAdd(&protos_un[(size_t)(d0 + 4*dg + i)*CCLS + 4*cg + j], acc[i][j]);
  }
}

// ---------------- 10. protos normalize ----------------
__global__ __launch_bounds__(256)
void k_protos_norm(const float* __restrict__ protos_un, const float* __restrict__ colsum,
                   float* __restrict__ protos_t){
  int c = blockIdx.x, t = threadIdx.x;
  __shared__ float sh4[4];
  float cs = fmaxf(colsum[c], FEPS);
  float v[4];
  float ss = 0.f;
  #pragma unroll
  for (int i=0;i<4;++i){
    int d = t + 256*i;
    v[i] = protos_un[(size_t)d*CCLS + c] / cs;
    ss += v[i]*v[i];
  }
  ss = blockSum256(ss, sh4);
  float inv = 1.0f / fmaxf(sqrtf(ss), FEPS);
  #pragma unroll
  for (int i=0;i<4;++i){
    int d = t + 256*i;
    protos_t[(size_t)c*DDIM + d] = v[i]*inv;
  }
}

// ---------------- 11. loss2 ----------------
__global__ __launch_bounds__(256)
void k_loss2(const float* __restrict__ feats, const float* __restrict__ protos_t,
             const int* __restrict__ pred, const float* __restrict__ w_c,
             const float* __restrict__ fnorm, float* __restrict__ scal){
  int row = blockIdx.x, t = threadIdx.x;
  float wc = w_c[row];
  if (wc == 0.f) return;
  __shared__ __align__(16) float f[DDIM];
  __shared__ float z[CCLS];
  float inv = 1.0f / fmaxf(fnorm[row], FEPS);
  { float4 v = ((const float4*)(feats + (size_t)row*DDIM))[t];
    v.x*=inv; v.y*=inv; v.z*=inv; v.w*=inv;
    ((float4*)f)[t] = v; }
  __syncthreads();
  int w = t >> 6, lane = t & 63;
  for (int ci=0; ci<16; ++ci){
    int c = w*16+ci;
    const float4* pc = (const float4*)(protos_t + (size_t)c*DDIM);
    float d = 0.f;
    #pragma unroll
    for (int j=0;j<4;++j){
      float4 a = pc[lane + 64*j];
      float4 b = ((float4*)f)[lane + 64*j];
      d += a.x*b.x+a.y*b.y+a.z*b.z+a.w*b.w;
    }
    d = waveSum(d);
    if (lane==0) z[c] = d;
  }
  __syncthreads();
  if (w == 0){
    float zz = z[lane];
    float m = waveMax(zz);
    float sv = waveSum(expf(zz - m));
    if (lane == 0){
      float lse = m + logf(sv);
      float ce = lse - z[pred[row]];
      atomicAdd(&scal[SC_L2NUM], ce * wc);
    }
  }
}

// ---------------- 12. sim stage-1: f16-hi single-pass MFMA, 256x256 tile,
//   16 waves (4x4), BK=64 (2 k-tiles per barrier-iteration, 16 iterations),
//   gload_lds dbuf from K-tiled pre-swizzled operands, per-chunk top-6 ----------------
// Buffer b (32768 halves = 64KB): A0 [0,8192) A1 [8192,16384) B0 [16384,24576) B1 [24576,32768)
__global__ __launch_bounds__(1024, 1)
void k_sim_approx(const _Float16* __restrict__ ht, const float* __restrict__ snm,
                  float* __restrict__ cval, int* __restrict__ cidx){
  __shared__ __align__(16) _Float16 smem[2*32768 + 512];   // 128KB bufs + 1KB sns
  float* sns = (float*)(smem + 2*32768);
  int t = threadIdx.x;
  int w = t >> 6, lane = t & 63;
  int wr = w >> 2, wcn = w & 3;
  int l31 = lane & 31, hi = lane >> 5;
  int bidl = blockIdx.y * 48 + blockIdx.x;
  int xcd = bidl & 7, lin = bidl >> 3;
  int yb = xcd * 2 + (lin / 48);
  int xb = lin - (lin / 48) * 48;
  int m0 = xb * 256, n0 = yb * 256;
  if (t < 256) sns[t] = snm[m0 + t];
  const _Float16* Abase = ht + (size_t)(m0 + w*16)*32 + (size_t)lane*8;
  const _Float16* Bbase = ht + (size_t)(NSUP + n0 + w*16)*32 + (size_t)lane*8;
  f32x16 acc[2][2];
  #pragma unroll
  for (int i=0;i<2;++i){
    #pragma unroll
    for (int j=0;j<2;++j) acc[i][j] = (f32x16)(0.f);
  }

  // stage k-tiles 2*t2 and 2*t2+1 into buffer b (4 gloads per wave, 4KB/wave)
  #define SIM_ST(b, t2) do {                                                      \
    _Pragma("unroll")                                                             \
    for (int j_ = 0; j_ < 2; ++j_){                                               \
      size_t ko = (size_t)(2*(t2)+j_)*(NTOT*32);                                  \
      __builtin_amdgcn_global_load_lds(                                           \
        (const __attribute__((address_space(1))) void*)(Abase + ko),              \
        (__attribute__((address_space(3))) void*)(smem + (b)*32768 + j_*8192 + w*512), 16,0,0);\
      __builtin_amdgcn_global_load_lds(                                           \
        (const __attribute__((address_space(1))) void*)(Bbase + ko),              \
        (__attribute__((address_space(3))) void*)(smem + (b)*32768 + 16384 + j_*8192 + w*512), 16,0,0);\
    }                                                                             \
  } while(0)

  SIM_ST(0, 0);
  for (int t2 = 0; t2 < 16; ++t2){
    const _Float16* buf = smem + (t2&1)*32768;
    __syncthreads();                      // drains vmcnt: both k-tiles landed (all waves)
    // ---- k-tile sub-step j=0: read frags, issue prefetch, MFMA ----
    half8_t af[2][2], bf[2][2];
    #pragma unroll
    for (int p=0;p<2;++p){
      int Ra = wr*64 + p*32 + l31;
      int sw = (Ra>>3)&3;
      #pragma unroll
      for (int kf=0;kf<2;++kf)
        af[p][kf] = *(const half8_t*)(buf + Ra*32 + (((kf*2+hi)^sw))*8);
    }
    #pragma unroll
    for (int ni=0;ni<2;++ni){
      int Rb = wcn*64 + ni*32 + l31;
      int sw = (Rb>>3)&3;
      #pragma unroll
      for (int kf=0;kf<2;++kf)
        bf[ni][kf] = *(const half8_t*)(buf + 16384 + Rb*32 + (((kf*2+hi)^sw))*8);
    }
    if (t2 < 15) SIM_ST((t2+1)&1, t2+1);  // lands during 2 MFMA sub-steps + next wait
    __builtin_amdgcn_s_setprio(1);
    #pragma unroll
    for (int p=0;p<2;++p){
      #pragma unroll
      for (int ni=0;ni<2;++ni){
        #pragma unroll
        for (int kf=0;kf<2;++kf)
          acc[p][ni] = __builtin_amdgcn_mfma_f32_32x32x16_f16(af[p][kf], bf[ni][kf], acc[p][ni], 0,0,0);
      }
    }
    __builtin_amdgcn_s_setprio(0);
    // ---- k-tile sub-step j=1 ----
    #pragma unroll
    for (int p=0;p<2;++p){
      int Ra = wr*64 + p*32 + l31;
      int sw = (Ra>>3)&3;
      #pragma unroll
      for (int kf=0;kf<2;++kf)
        af[p][kf] = *(const half8_t*)(buf + 8192 + Ra*32 + (((kf*2+hi)^sw))*8);
    }
    #pragma unroll
    for (int ni=0;ni<2;++ni){
      int Rb = wcn*64 + ni*32 + l31;
      int sw = (Rb>>3)&3;
      #pragma unroll
      for (int kf=0;kf<2;++kf)
        bf[ni][kf] = *(const half8_t*)(buf + 24576 + Rb*32 + (((kf*2+hi)^sw))*8);
    }
    __builtin_amdgcn_s_setprio(1);
    #pragma unroll
    for (int p=0;p<2;++p){
      #pragma unroll
      for (int ni=0;ni<2;++ni){
        #pragma unroll
        for (int kf=0;kf<2;++kf)
          acc[p][ni] = __builtin_amdgcn_mfma_f32_32x32x16_f16(af[p][kf], bf[ni][kf], acc[p][ni], 0,0,0);
      }
    }
    __builtin_amdgcn_s_setprio(0);
  }
  #undef SIM_ST
  // ---- epilogue: mask+scale (order-preserving per col), per-chunk top-6 ----
  // C layout (32x32): col = lane&31, row = (reg&3) + 8*(reg>>2) + 4*(lane>>5)
  __syncthreads();
  float tv[2][6]; int ti[2][6];
  #pragma unroll
  for (int ni=0;ni<2;++ni){
    #pragma unroll
    for (int k=0;k<6;++k){ tv[ni][k] = -INFINITY; ti[ni][k] = 0x7fffffff; }
  }
  #pragma unroll
  for (int ni=0;ni<2;++ni){
    #pragma unroll
    for (int p=0;p<2;++p){
      #pragma unroll
      for (int r=0;r<16;++r){
        int rl = wr*64 + p*32 + (r&3) + 8*(r>>2) + 4*hi;
        float sn = sns[rl];
        float v = acc[p][ni][r] * fabsf(sn);
        v = (sn > 0.f) ? v : -INFINITY;
        top6_insert(tv[ni], ti[ni], v, m0 + rl);
      }
    }
  }
  // merge lane^32 (same col, other hi)
  #pragma unroll
  for (int ni=0;ni<2;++ni){
    float pv[6]; int pi[6];
    #pragma unroll
    for (int k=0;k<6;++k){ pv[k] = __shfl_xor(tv[ni][k], 32); pi[k] = __shfl_xor(ti[ni][k], 32); }
    #pragma unroll
    for (int k=0;k<6;++k) top6_insert(tv[ni], ti[ni], pv[k], pi[k]);
  }
  // cross-wr merge via LDS: [256 cols][stride 25], slots wr*6+k (24 used + 1 pad)
  float* MV = (float*)smem;
  int*   MI = (int*)smem + 6400;
  if (hi == 0){
    #pragma unroll
    for (int ni=0;ni<2;++ni){
      int col = wcn*64 + ni*32 + l31;
      #pragma unroll
      for (int k=0;k<6;++k){
        MV[col*25 + wr*6 + k] = tv[ni][k];
        MI[col*25 + wr*6 + k] = ti[ni][k];
      }
    }
  }
  __syncthreads();
  if (t < 256){
    float bv[6]; int bi[6];
    #pragma unroll
    for (int k=0;k<6;++k){ bv[k] = -INFINITY; bi[k] = 0x7fffffff; }
    for (int j = 0; j < 24; ++j) top6_insert(bv, bi, MV[t*25 + j], MI[t*25 + j]);
    float* co = cval + (size_t)(n0 + t)*KCAND + xb*6;
    int*   ci = cidx + (size_t)(n0 + t)*KCAND + xb*6;
    #pragma unroll
    for (int k=0;k<6;++k){ co[k] = bv[k]; ci[k] = bi[k]; }
  }
}

// ---------------- 13. stage-2: approx top-10 -> exact fp32 rescore -> top-5 -> NCL ----------------
__global__ __launch_bounds__(256)
void k_rescore_ncl(const float* __restrict__ cval, const int* __restrict__ cidx,
                   const float* __restrict__ sup, const float* __restrict__ feats,
                   const float* __restrict__ rb, const float* __restrict__ snm,
                   const float* __restrict__ scores_old, const float* __restrict__ probs,
                   const float* __restrict__ logp, const float* __restrict__ w_c,
                   float* __restrict__ scal){
  int t = threadIdx.x, w = t >> 6, lane = t & 63;
  int b = blockIdx.x*4 + w;
  // load candidates (KCAND=288 -> 5 per lane, last partial)
  float lv[5]; int li[5];
  #pragma unroll
  for (int j=0;j<5;++j){
    int idx = lane + 64*j;
    bool ok = idx < KCAND;
    lv[j] = ok ? cval[(size_t)b*KCAND + idx] : -INFINITY;
    li[j] = ok ? cidx[(size_t)b*KCAND + idx] : 0x7fffffff;
  }
  // per-lane sort descending (5 elems)
  #pragma unroll
  for (int a=0;a<4;++a){
    #pragma unroll
    for (int c=0;c<4-a;++c){
      bool sw = lv[c+1] > lv[c];
      float fv = sw ? lv[c+1] : lv[c];  float fw = sw ? lv[c] : lv[c+1];
      int   iv = sw ? li[c+1] : li[c];  int   iw = sw ? li[c] : li[c+1];
      lv[c]=fv; lv[c+1]=fw; li[c]=iv; li[c+1]=iw;
    }
  }
  // extract global approx top-10
  float t10v[10]; int t10i[10];
  int head = 0;
  #pragma unroll
  for (int k=0;k<10;++k){
    float hv = -INFINITY; int hidx = 0x7fffffff;
    switch(head){
      case 0: hv=lv[0]; hidx=li[0]; break;
      case 1: hv=lv[1]; hidx=li[1]; break;
      case 2: hv=lv[2]; hidx=li[2]; break;
      case 3: hv=lv[3]; hidx=li[3]; break;
      case 4: hv=lv[4]; hidx=li[4]; break;
      default: break;
    }
    float m = waveMax(hv);
    unsigned long long bal = __ballot(hv == m);
    int wl = __ffsll(bal) - 1;
    t10v[k] = m;
    t10i[k] = __shfl(hidx, wl);
    if (lane == wl) head++;
  }
  (void)t10v;
  // exact fp32 rescore of the 10
  float4 fr0 = *(const float4*)(feats + (size_t)b*DDIM + lane*16);
  float4 fr1 = *(const float4*)(feats + (size_t)b*DDIM + lane*16 + 4);
  float4 fr2 = *(const float4*)(feats + (size_t)b*DDIM + lane*16 + 8);
  float4 fr3 = *(const float4*)(feats + (size_t)b*DDIM + lane*16 + 12);
  float rbv = rb[b];
  float ev[10];
  #pragma unroll
  for (int c=0;c<10;++c){
    int idx = t10i[c];
    const float* srow = (idx < NSUP) ? (sup + (size_t)idx*DDIM)
                                     : (feats + (size_t)(idx-NSUP)*DDIM);
    float4 s0 = *(const float4*)(srow + lane*16);
    float4 s1 = *(const float4*)(srow + lane*16 + 4);
    float4 s2 = *(const float4*)(srow + lane*16 + 8);
    float4 s3 = *(const float4*)(srow + lane*16 + 12);
    float d = fr0.x*s0.x + fr0.y*s0.y + fr0.z*s0.z + fr0.w*s0.w
            + fr1.x*s1.x + fr1.y*s1.y + fr1.z*s1.z + fr1.w*s1.w
            + fr2.x*s2.x + fr2.y*s2.y + fr2.z*s2.z + fr2.w*s2.w
            + fr3.x*s3.x + fr3.y*s3.y + fr3.z*s3.z + fr3.w*s3.w;
    d = waveSum(d);
    ev[c] = d * rbv * fabsf(snm[idx]);
  }
  // select top-5 exact with reference tie-break (value desc, then index asc)
  int used = 0;
  int sel[5];
  #pragma unroll
  for (int k=0;k<5;++k){
    float bb = -INFINITY; int bbi = 0x7fffffff; int bj = 0;
    #pragma unroll
    for (int j=0;j<10;++j){
      bool free_ = !((used >> j) & 1);
      bool better = free_ && ((ev[j] > bb) || (ev[j] == bb && t10i[j] < bbi));
      bb  = better ? ev[j]   : bb;
      bbi = better ? t10i[j] : bbi;
      bj  = better ? j       : bj;
    }
    used |= (1 << bj);
    sel[k] = bbi;
  }
  // NCL
  float tg = 0.f;
  #pragma unroll
  for (int k=0;k<5;++k){
    int ix = sel[k];
    const float* srow = (ix < NSUP) ? (scores_old + (size_t)ix*CCLS)
                                    : (probs + (size_t)(ix-NSUP)*CCLS);
    tg += srow[lane];
  }
  tg *= 0.2f;
  float d = tg * logp[(size_t)b*CCLS + lane];
  d = waveSum(d);
  if (lane == 0) atomicAdd(&scal[SC_L3NUM], -d * (1.0f - w_c[b]));
}

// ---------------- 14. final combine ----------------
__global__ void k_final(const float* __restrict__ pm_acc, const float* __restrict__ scal,
                        float* __restrict__ out){
  int lane = threadIdx.x;  // 64 threads
  float pm = pm_acc[lane] * (1.0f/BBATCH);
  float dterm = pm * logf(pm + FEPS);
  float dv = waveSum(dterm);
  if (lane == 0){
    float div = -dv;
    float tsallis = scal[SC_TSAL] * (1.0f/BBATCH);
    float swc = scal[SC_SUMWC];
    float l1 = tsallis - div;
    float l2 = scal[SC_L2NUM] / fmaxf(swc, 1.0f);
    float l3 = scal[SC_L3NUM] / fmaxf((float)BBATCH - swc, 1.0f);
    out[0] = l1 + l2 + l3;
  }
}

// ---------------- launch ----------------
extern "C" void kernel_launch(void* const* d_in, const int* in_sizes, int n_in,
                              void* d_out, int out_size, void* d_ws, size_t ws_size,
                              hipStream_t stream){
  (void)in_sizes; (void)n_in; (void)out_size; (void)ws_size;
  const float* x      = (const float*)d_in[0];
  // d_in[1] = y (unused by the reference loss)
  const float* Wf     = (const float*)d_in[2];
  const float* Wc     = (const float*)d_in[3];
  const float* bc     = (const float*)d_in[4];
  const float* sup    = (const float*)d_in[5];
  const float* labels = (const float*)d_in[6];
  const float* scores = (const float*)d_in[7];
  float* ws = (float*)d_ws;

  float* feats  = ws + OFF_FEATS;
  float* featp1 = ws + OFF_FEATP1;
  unsigned short* wfth = (unsigned short*)(ws + OFF_WFTH);
  unsigned short* wftl = (unsigned short*)(ws + OFF_WFTL);
  _Float16* ht  = (_Float16*)(ws + OFF_HT);
  float* probs  = ws + OFF_PROBS;
  float* logp   = ws + OFF_LOGP;
  float* fnorm  = ws + OFF_FNORM;
  float* snorm  = ws + OFF_SNORM;
  float* pmax   = ws + OFF_PMAX;
  float* e_row  = ws + OFF_EROW;
  float* w_c    = ws + OFF_WC;
  int*   pred   = (int*)(ws + OFF_PRED);
  float* rb     = ws + OFF_RB;
  float* snm    = ws + OFF_SNM;
  float* protot = ws + OFF_PROTOT;
  float* cvalp  = ws + OFF_CVAL;
  int*   cidxp  = (int*)(ws + OFF_CIDX);
  float* m_acc  = ws + OFF_MACC;
  float* pm_acc = ws + OFF_PMACC;
  float* colsum = ws + OFF_COLS;
  float* scal   = ws + OFF_SCAL;
  float* protun = ws + OFF_PROTUN;

  hipMemsetAsync(ws + OFF_ZERO, 0, (OFF_ZEND - OFF_ZERO)*sizeof(float), stream);

  k_entropy      <<<BBATCH, 256, 0, stream>>>(x, e_row, scal);
  k_wft          <<<dim3(DDIM/64, LLEN/64), 256, 0, stream>>>(Wf, wfth, wftl);
  k_feats_mfma   <<<dim3(DDIM/128, BBATCH/128, 2), 256, 0, stream>>>(x, wfth, wftl, feats);
  k_supnorm      <<<NSUP/4, 256, 0, stream>>>(sup, snorm, ht);
  k_logits       <<<BBATCH, 256, 0, stream>>>(feats, featp1, Wc, bc, probs, logp, pmax, pred, fnorm, scal, ht);
  k_mask         <<<32, 256, 0, stream>>>(e_row, pmax, fnorm, snorm, pred, w_c, rb, snm, colsum, scal);
  k_colsum_labels<<<32, 256, 0, stream>>>(labels, colsum);
  k_m_accum      <<<64, 256, 0, stream>>>(probs, w_c, m_acc);
  k_loss1        <<<64, 256, 0, stream>>>(probs, m_acc, pm_acc, scal);
  k_protos_gemm  <<<dim3(16, 8), 256, 0, stream>>>(sup, feats, labels, pred, w_c, snm, protun);
  k_protos_norm  <<<CCLS, 256, 0, stream>>>(protun, colsum, protot);
  k_loss2        <<<BBATCH, 256, 0, stream>>>(feats, protot, pred, w_c, fnorm, scal);
  k_sim_approx   <<<dim3(48, 16), 1024, 0, stream>>>(ht, snm, cvalp, cidxp);
  k_rescore_ncl  <<<BBATCH/4, 256, 0, stream>>>(cvalp, cidxp, sup, feats, rb, snm, scores, probs, logp, w_c, scal);
  k_final        <<<1, 64, 0, stream>>>(pm_acc, scal, (float*)d_out);
}

// Round 17
// 817.944 us; speedup vs baseline: 1.0686x; 1.0686x over previous
//
#include <hip/hip_runtime.h>
#include <math.h>

// ---------------- problem constants ----------------
#define BBATCH 4096
#define LLEN   4096
#define DDIM   1024
#define CCLS   64
#define NSUP   8192
#define NTOT   12288            // NSUP + BBATCH
#define FEPS   1e-12f
#define KCHUNK 48               // NTOT / 256 support chunks
#define KCAND  (KCHUNK*6)       // 288 candidates per row

// scalar accumulator slots
#define SC_SUMP  0
#define SC_SUME  1
#define SC_SUMWC 2
#define SC_TSAL  3
#define SC_L2NUM 4
#define SC_L3NUM 5

typedef _Float16 half4_t __attribute__((ext_vector_type(4)));
typedef _Float16 half8_t __attribute__((ext_vector_type(8)));
typedef float    f32x4   __attribute__((ext_vector_type(4)));
typedef float    f32x16  __attribute__((ext_vector_type(16)));

// ---------------- workspace layout (float offsets) ----------------
static const size_t OFF_FEATS  = 0;                                    // B*D
static const size_t OFF_FEATP1 = OFF_FEATS  + (size_t)BBATCH*DDIM;     // B*D
static const size_t OFF_WFTH   = OFF_FEATP1 + (size_t)BBATCH*DDIM;     // D*L halves
static const size_t OFF_WFTL   = OFF_WFTH   + (size_t)DDIM*LLEN/2;     // D*L halves
static const size_t OFF_PROBS  = OFF_WFTL   + (size_t)DDIM*LLEN/2;     // B*C
static const size_t OFF_LOGP   = OFF_PROBS  + (size_t)BBATCH*CCLS;     // B*C
static const size_t OFF_FNORM  = OFF_LOGP   + (size_t)BBATCH*CCLS;     // B
static const size_t OFF_SNORM  = OFF_FNORM  + BBATCH;                  // N
static const size_t OFF_PMAX   = OFF_SNORM  + NSUP;                    // B
static const size_t OFF_EROW   = OFF_PMAX   + BBATCH;                  // B
static const size_t OFF_WC     = OFF_EROW   + BBATCH;                  // B
static const size_t OFF_PRED   = OFF_WC     + BBATCH;                  // B (int)
static const size_t OFF_RB     = OFF_PRED   + BBATCH;                  // B
static const size_t OFF_SNM    = OFF_RB     + BBATCH;                  // NTOT
static const size_t OFF_PROTOT = OFF_SNM    + NTOT;                    // C*D
static const size_t OFF_CVAL   = OFF_PROTOT + (size_t)CCLS*DDIM;       // B*KCAND
static const size_t OFF_CIDX   = OFF_CVAL   + (size_t)BBATCH*KCAND;    // B*KCAND (int)
static const size_t OFF_ZERO   = OFF_CIDX   + (size_t)BBATCH*KCAND;    // zeroed region:
static const size_t OFF_MACC   = OFF_ZERO;                             // C
static const size_t OFF_PMACC  = OFF_MACC   + CCLS;                    // C
static const size_t OFF_COLS   = OFF_PMACC  + CCLS;                    // C
static const size_t OFF_SCAL   = OFF_COLS   + CCLS;                    // 32
static const size_t OFF_PROTUN = OFF_SCAL   + 32;                      // D*C
static const size_t OFF_ZEND   = OFF_PROTUN + (size_t)DDIM*CCLS;       // end zeroed
static const size_t OFF_HT     = OFF_ZEND;                             // 32*NTOT*32 halves (25.2MB)
static const size_t WS_END     = OFF_HT + (size_t)32*NTOT*32/2;

// ---------------- helpers ----------------
__device__ __forceinline__ float waveSum(float v){
  #pragma unroll
  for (int o = 32; o > 0; o >>= 1) v += __shfl_xor(v, o);
  return v;
}
__device__ __forceinline__ float waveMax(float v){
  #pragma unroll
  for (int o = 32; o > 0; o >>= 1) v = fmaxf(v, __shfl_xor(v, o));
  return v;
}
__device__ __forceinline__ float blockSum256(float v, float* sh4){
  v = waveSum(v);
  if ((threadIdx.x & 63) == 0) sh4[threadIdx.x >> 6] = v;
  __syncthreads();
  float r = sh4[0] + sh4[1] + sh4[2] + sh4[3];
  __syncthreads();
  return r;
}
// branchless top-6 insertion (strict > keeps earlier-inserted on ties)
__device__ __forceinline__ void top6_insert(float* v, int* ix, float s, int si){
  bool c0=s>v[0],c1=s>v[1],c2=s>v[2],c3=s>v[3],c4=s>v[4],c5=s>v[5];
  v[5]=c5?(c4?v[4]:s):v[5]; ix[5]=c5?(c4?ix[4]:si):ix[5];
  v[4]=c4?(c3?v[3]:s):v[4]; ix[4]=c4?(c3?ix[3]:si):ix[4];
  v[3]=c3?(c2?v[2]:s):v[3]; ix[3]=c3?(c2?ix[2]:si):ix[3];
  v[2]=c2?(c1?v[1]:s):v[2]; ix[2]=c2?(c1?ix[1]:si):ix[2];
  v[1]=c1?(c0?v[0]:s):v[1]; ix[1]=c1?(c0?ix[0]:si):ix[1];
  v[0]=c0?s:v[0];           ix[0]=c0?si:ix[0];
}
// fp32 -> f16 hi + f16 lo (residual)
__device__ __forceinline__ void split4(const float4 v, half4_t* h, half4_t* l){
  half4_t hh, ll;
  hh[0] = (_Float16)v.x; hh[1] = (_Float16)v.y; hh[2] = (_Float16)v.z; hh[3] = (_Float16)v.w;
  ll[0] = (_Float16)(v.x - (float)hh[0]);
  ll[1] = (_Float16)(v.y - (float)hh[1]);
  ll[2] = (_Float16)(v.z - (float)hh[2]);
  ll[3] = (_Float16)(v.w - (float)hh[3]);
  *h = hh; *l = ll;
}
// ht tiled layout: element (row, d) -> kt=d>>5 tile, row-major 32-half rows,
// 8-half slots XOR-swizzled by ((row>>3)&3) for conflict-free ds_read_b128.
__device__ __forceinline__ size_t ht_off(int row, int d){
  int kt = d >> 5;
  int slot = ((d >> 3) & 3) ^ ((row >> 3) & 3);
  return (size_t)kt * (NTOT*32) + (size_t)row * 32 + slot*8 + (d & 7);
}

// ---------------- 1. per-row input-energy entropy ----------------
__global__ __launch_bounds__(256)
void k_entropy(const float* __restrict__ x, float* __restrict__ e_row,
               float* __restrict__ scal){
  __shared__ __align__(16) float lx[LLEN];
  __shared__ float sh4[4];
  int row = blockIdx.x, t = threadIdx.x;
  const float4* xr = (const float4*)(x + (size_t)row * LLEN);
  float s = 0.f;
  #pragma unroll
  for (int i = 0; i < 4; ++i){
    float4 v = xr[t + 256*i];
    ((float4*)lx)[t + 256*i] = v;
    s += v.x*v.x + v.y*v.y + v.z*v.z + v.w*v.w;
  }
  s = blockSum256(s, sh4);
  float inv = 1.0f / fmaxf(s, FEPS);
  float ent = 0.f;
  #pragma unroll
  for (int i = 0; i < 4; ++i){
    float4 v = ((float4*)lx)[t + 256*i];
    float p;
    p = v.x*v.x*inv; ent -= p * logf(p + 1e-30f);
    p = v.y*v.y*inv; ent -= p * logf(p + 1e-30f);
    p = v.z*v.z*inv; ent -= p * logf(p + 1e-30f);
    p = v.w*v.w*inv; ent -= p * logf(p + 1e-30f);
  }
  ent = blockSum256(ent, sh4);
  if (t == 0){ e_row[row] = ent; atomicAdd(&scal[SC_SUME], ent); }
}

// ---------------- 2a. Wf transpose + f16 split ----------------
__global__ __launch_bounds__(256)
void k_wft(const float* __restrict__ Wf, unsigned short* __restrict__ WftH,
           unsigned short* __restrict__ WftL){
  __shared__ __align__(16) float ld[64*68];
  int t = threadIdx.x;
  int d0 = blockIdx.x * 64;
  int l0 = blockIdx.y * 64;
  #pragma unroll
  for (int i = 0; i < 4; ++i){
    int flat = t + 256*i;
    int l = flat >> 4, d4 = (flat & 15) * 4;
    *(float4*)&ld[l*68 + d4] = *(const float4*)(Wf + (size_t)(l0+l)*DDIM + d0 + d4);
  }
  __syncthreads();
  #pragma unroll
  for (int i = 0; i < 4; ++i){
    int flat = t + 256*i;
    int d = flat >> 4, l4 = (flat & 15) * 4;
    float4 v = make_float4(ld[(l4+0)*68 + d], ld[(l4+1)*68 + d],
                           ld[(l4+2)*68 + d], ld[(l4+3)*68 + d]);
    half4_t h, l;
    split4(v, &h, &l);
    *(half4_t*)(WftH + (size_t)(d0+d)*LLEN + l0 + l4) = h;
    *(half4_t*)(WftL + (size_t)(d0+d)*LLEN + l0 + l4) = l;
  }
}

// ---------------- 2b. feats = x @ Wf via f16x3 MFMA (32x32x16), K-split x2 ----------------
// XCD-grouped remap: XCD k owns m-panels {k, k+8, k+16, k+24}; all 16 (n,kz)
// consumers of one m-panel co-resident on that XCD -> A panel L2-resident.
// A (x fp32) staged via global_load_lds with source granule-XOR pre-swizzle;
// f32 -> h/l split in regs on LDS read-back. B (Wft h/l) gload.
// LDS per buffer (halves): Af32 [0,8192), Bh [8192,12288), Bl [12288,16384).
__global__ __launch_bounds__(256)
void k_feats_mfma(const float* __restrict__ X, const unsigned short* __restrict__ WftHu,
                  const unsigned short* __restrict__ WftLu, float* __restrict__ featp){
  __shared__ __align__(16) _Float16 lds[2*16384];   // 64KB
  int t = threadIdx.x;
  // bijective dispatch remap (grid 8x32x2 -> 512 linear ids, XCD = id&7)
  int aid = blockIdx.x + 8*blockIdx.y + 256*blockIdx.z;
  int xcd = aid & 7;
  int s_  = aid >> 3;               // 0..63
  int my  = xcd + 8*(s_ >> 4);      // m-panel 0..31 (XCD-local)
  int r_  = s_ & 15;
  int n0 = (r_ & 7) * 128;
  int m0 = my * 128;
  int kz = r_ >> 3;
  int w = t >> 6, lane = t & 63;
  int wr = w >> 1, wc = w & 1;
  int l31 = lane & 31, hi = lane >> 5;
  const _Float16* Bgh = (const _Float16*)WftHu + (size_t)n0*LLEN;
  const _Float16* Bgl = (const _Float16*)WftLu + (size_t)n0*LLEN;
  const size_t glRowB = (size_t)(lane >> 2)*LLEN;
  int arow = lane >> 3;
  int agr  = (lane & 7) ^ (arow & 7);
  f32x16 acc[2][2];
  #pragma unroll
  for (int i=0;i<2;++i){
    #pragma unroll
    for (int j=0;j<2;++j) acc[i][j] = (f32x16)(0.f);
  }
  const int kstart = kz*2048;

  #define STAGE_AB(bufi, k0c) do {                                                 \
    _Float16* Lb = lds + (bufi)*16384;                                             \
    _Pragma("unroll")                                                              \
    for (int g = 0; g < 4; ++g){                                                   \
      const float* asrc = X + (size_t)(m0 + w*32 + g*8 + arow)*LLEN + (k0c) + 4*agr;\
      __builtin_amdgcn_global_load_lds(                                            \
        (const __attribute__((address_space(1))) void*)asrc,                       \
        (__attribute__((address_space(3))) void*)(Lb + (w*32 + g*8)*64), 16,0,0);  \
    }                                                                              \
    _Pragma("unroll")                                                              \
    for (int s2 = 0; s2 < 2; ++s2){                                                \
      int blk = s2*4 + w;                                                          \
      int csrc = (lane & 3) ^ ((blk*2 + (lane >> 5)) & 3);                         \
      size_t go = glRowB + (size_t)blk*16*LLEN + (k0c) + (size_t)csrc*8;           \
      __builtin_amdgcn_global_load_lds(                                            \
        (const __attribute__((address_space(1))) void*)(Bgh + go),                 \
        (__attribute__((address_space(3))) void*)(Lb + 8192 + blk*512), 16,0,0);   \
      __builtin_amdgcn_global_load_lds(                                            \
        (const __attribute__((address_space(1))) void*)(Bgl + go),                 \
        (__attribute__((address_space(3))) void*)(Lb + 12288 + blk*512), 16,0,0);  \
    }                                                                              \
  } while(0)

  STAGE_AB(0, kstart);
  for (int it = 0; it < 64; ++it){
    const _Float16* buf = lds + (it&1)*16384;
    __syncthreads();                     // tile it fully landed (vmcnt drained)
    const float* Af = (const float*)buf;
    half8_t ah[2][2], al[2][2];
    #pragma unroll
    for (int p_=0;p_<2;++p_){
      int Ra = wr*64 + p_*32 + l31;
      int rx = Ra & 7;
      #pragma unroll
      for (int kf=0;kf<2;++kf){
        int g0 = kf*4 + hi*2;
        f32x4 v0 = *(const f32x4*)(Af + Ra*32 + 4*((g0  ) ^ rx));
        f32x4 v1 = *(const f32x4*)(Af + Ra*32 + 4*((g0+1) ^ rx));
        half8_t h, l;
        #pragma unroll
        for (int j=0;j<4;++j){
          h[j]   = (_Float16)v0[j]; l[j]   = (_Float16)(v0[j] - (float)h[j]);
          h[4+j] = (_Float16)v1[j]; l[4+j] = (_Float16)(v1[j] - (float)h[4+j]);
        }
        ah[p_][kf] = h; al[p_][kf] = l;
      }
    }
    half8_t bh[2][2], bl[2][2];
    #pragma unroll
    for (int ni=0;ni<2;++ni){
      int Rb = wc*64 + ni*32 + l31;
      int sw = (Rb>>3)&3;
      #pragma unroll
      for (int kf=0;kf<2;++kf){
        int sc = (kf*2 + hi) ^ sw;
        bh[ni][kf] = *(const half8_t*)(buf + 8192  + Rb*32 + sc*8);
        bl[ni][kf] = *(const half8_t*)(buf + 12288 + Rb*32 + sc*8);
      }
    }
    if (it < 63) STAGE_AB((it+1)&1, kstart + (it+1)*32);
    __builtin_amdgcn_s_setprio(1);
    #pragma unroll
    for (int p_=0;p_<2;++p_){
      #pragma unroll
      for (int ni=0;ni<2;++ni){
        #pragma unroll
        for (int kf=0;kf<2;++kf){
          acc[p_][ni] = __builtin_amdgcn_mfma_f32_32x32x16_f16(ah[p_][kf], bh[ni][kf], acc[p_][ni], 0,0,0);
          acc[p_][ni] = __builtin_amdgcn_mfma_f32_32x32x16_f16(ah[p_][kf], bl[ni][kf], acc[p_][ni], 0,0,0);
          acc[p_][ni] = __builtin_amdgcn_mfma_f32_32x32x16_f16(al[p_][kf], bh[ni][kf], acc[p_][ni], 0,0,0);
        }
      }
    }
    __builtin_amdgcn_s_setprio(0);
  }
  #undef STAGE_AB
  // C layout (32x32): col = lane&31, row = (reg&3) + 8*(reg>>2) + 4*(lane>>5)
  float* outp = featp + (size_t)kz * BBATCH * DDIM;
  #pragma unroll
  for (int mi=0;mi<2;++mi){
    #pragma unroll
    for (int ni=0;ni<2;++ni){
      #pragma unroll
      for (int r=0;r<16;++r){
        int row = m0 + wr*64 + mi*32 + (r&3) + 8*(r>>2) + 4*hi;
        int col = n0 + wc*64 + ni*32 + l31;
        outp[(size_t)row*DDIM + col] = acc[mi][ni][r];
      }
    }
  }
}

// ---------------- 3. support row norms + f16-hi tiled pack ----------------
__global__ __launch_bounds__(256)
void k_supnorm(const float* __restrict__ sup, float* __restrict__ snorm,
               _Float16* __restrict__ ht){
  int w = threadIdx.x >> 6, lane = threadIdx.x & 63;
  int row = blockIdx.x*4 + w;
  const float4* rp = (const float4*)(sup + (size_t)row * DDIM);
  float s = 0.f;
  #pragma unroll
  for (int j=0;j<4;++j){
    float4 v = rp[lane + 64*j];
    half4_t h;
    h[0]=(_Float16)v.x; h[1]=(_Float16)v.y; h[2]=(_Float16)v.z; h[3]=(_Float16)v.w;
    int d = (lane + 64*j)*4;
    *(half4_t*)(ht + ht_off(row, d)) = h;
    s += v.x*v.x+v.y*v.y+v.z*v.z+v.w*v.w;
  }
  s = waveSum(s);
  if (lane==0) snorm[row] = sqrtf(s);
}

// ---------------- 4. sum K-split partials -> feats (+f16-hi tiled pack); logits+softmax ----------------
__global__ __launch_bounds__(256)
void k_logits(float* __restrict__ feats, const float* __restrict__ featp1,
              const float* __restrict__ Wc,
              const float* __restrict__ bc, float* __restrict__ probs,
              float* __restrict__ logp, float* __restrict__ pmax,
              int* __restrict__ pred, float* __restrict__ fnorm,
              float* __restrict__ scal,
              _Float16* __restrict__ ht){
  __shared__ __align__(16) float f[DDIM];
  __shared__ float z[CCLS];
  __shared__ float sh4[4];
  int row = blockIdx.x, t = threadIdx.x;
  const float4* fr0 = (const float4*)(feats  + (size_t)row * DDIM);
  const float4* fr1 = (const float4*)(featp1 + (size_t)row * DDIM);
  float ss = 0.f;
  { float4 a = fr0[t], b = fr1[t];
    float4 v = make_float4(a.x+b.x, a.y+b.y, a.z+b.z, a.w+b.w);
    ((float4*)f)[t] = v;
    ((float4*)(feats + (size_t)row*DDIM))[t] = v;
    half4_t h;
    h[0]=(_Float16)v.x; h[1]=(_Float16)v.y; h[2]=(_Float16)v.z; h[3]=(_Float16)v.w;
    *(half4_t*)(ht + ht_off(NSUP + row, t*4)) = h;
    ss += v.x*v.x+v.y*v.y+v.z*v.z+v.w*v.w; }
  ss = blockSum256(ss, sh4);
  if (t==0) fnorm[row] = sqrtf(ss);
  int w = t >> 6, lane = t & 63;
  for (int ci = 0; ci < 16; ++ci){
    int c = w*16 + ci;
    const float4* wc = (const float4*)(Wc + (size_t)c * DDIM);
    float d = 0.f;
    #pragma unroll
    for (int j=0;j<4;++j){
      float4 a = wc[lane + 64*j];
      float4 b = ((float4*)f)[lane + 64*j];
      d += a.x*b.x+a.y*b.y+a.z*b.z+a.w*b.w;
    }
    d = waveSum(d);
    if (lane == 0) z[c] = d + bc[c];
  }
  __syncthreads();
  if (w == 0){
    float zz = z[lane];
    float m = waveMax(zz);
    unsigned long long bal = __ballot(zz == m);
    int am = __ffsll(bal) - 1;
    float ex = expf(zz - m);
    float sv = waveSum(ex);
    probs[(size_t)row*CCLS + lane] = ex / sv;
    logp[(size_t)row*CCLS + lane]  = (zz - m) - logf(sv);
    if (lane == 0){
      float pmv = 1.0f / sv;
      pmax[row] = pmv;
      pred[row] = am;
      atomicAdd(&scal[SC_SUMP], pmv);
    }
  }
}

// ---------------- 5. masks, scale factors ----------------
__global__ __launch_bounds__(256)
void k_mask(const float* __restrict__ e_row, const float* __restrict__ pmax,
            const float* __restrict__ fnorm, const float* __restrict__ snorm,
            const int* __restrict__ pred, float* __restrict__ w_c,
            float* __restrict__ rb, float* __restrict__ snm,
            float* __restrict__ colsum, float* __restrict__ scal){
  int i = blockIdx.x * 256 + threadIdx.x;
  if (i < NSUP) snm[i] = 1.0f / fmaxf(snorm[i], FEPS);
  if (i < BBATCH){
    float me = scal[SC_SUME] * (1.0f/BBATCH);
    float mp = scal[SC_SUMP] * (1.0f/BBATCH);
    float wc = ((e_row[i] < me) && (pmax[i] >= mp)) ? 1.0f : 0.0f;
    w_c[i] = wc;
    float fn = fmaxf(fnorm[i], FEPS);
    rb[i] = 10.0f / fn;
    snm[NSUP + i] = (wc > 0.f) ? (1.0f / fn) : -1.0f;
    atomicAdd(&scal[SC_SUMWC], wc);
    atomicAdd(&colsum[pred[i]], wc);
  }
}

// ---------------- 6. colsum over labels_old ----------------
__global__ __launch_bounds__(256)
void k_colsum_labels(const float* __restrict__ labels, float* __restrict__ colsum){
  int t = threadIdx.x, c = t & 63, sub = t >> 6;
  int r0 = blockIdx.x * 256;
  float s = 0.f;
  for (int i = 0; i < 64; ++i){
    int r = r0 + sub + 4*i;
    s += labels[(size_t)r*CCLS + c];
  }
  __shared__ float loc[4][64];
  loc[sub][c] = s;
  __syncthreads();
  if (sub == 0) atomicAdd(&colsum[c], loc[0][c]+loc[1][c]+loc[2][c]+loc[3][c]);
}

// ---------------- 7. m accumulator ----------------
__global__ __launch_bounds__(256)
void k_m_accum(const float* __restrict__ probs, const float* __restrict__ w_c,
               float* __restrict__ m_acc){
  int t = threadIdx.x, c = t & 63, sub = t >> 6;
  int r0 = blockIdx.x * 64;
  float s = 0.f;
  for (int i = 0; i < 16; ++i){
    int r = r0 + sub + 4*i;
    s += probs[(size_t)r*CCLS + c] * w_c[r];
  }
  __shared__ float loc[4][64];
  loc[sub][c] = s;
  __syncthreads();
  if (sub == 0) atomicAdd(&m_acc[c], loc[0][c]+loc[1][c]+loc[2][c]+loc[3][c]);
}

// ---------------- 8. loss1 pieces ----------------
__global__ __launch_bounds__(256)
void k_loss1(const float* __restrict__ probs, const float* __restrict__ m_acc,
             float* __restrict__ pm_acc, float* __restrict__ scal){
  int t = threadIdx.x, w = t >> 6, lane = t & 63;
  float swc = fmaxf(scal[SC_SUMWC], 1.0f);
  float minv = 1.0f / fmaxf(m_acc[lane] / swc, FEPS);
  float pml = 0.f, tsl = 0.f;
  int r0 = blockIdx.x * 64 + w * 16;
  for (int i = 0; i < 16; ++i){
    int r = r0 + i;
    float pb = probs[(size_t)r*CCLS + lane] * minv;
    float t1 = waveSum(pb);
    float t2 = waveSum(pb*pb);
    tsl += 1.0f - t2/(t1*t1);
    pml += pb/t1;
  }
  atomicAdd(&pm_acc[lane], pml);
  if (lane == 0) atomicAdd(&scal[SC_TSAL], tsl);
}

// ---------------- 9. protos GEMM ----------------
__global__ __launch_bounds__(256)
void k_protos_gemm(const float* __restrict__ sup, const float* __restrict__ feats,
                   const float* __restrict__ labels, const int* __restrict__ pred,
                   const float* __restrict__ w_c, const float* __restrict__ snm,
                   float* __restrict__ protos_un){
  __shared__ __align__(16) float ssx[64*68];
  __shared__ __align__(16) float sl[64*68];
  int t = threadIdx.x;
  int d0 = blockIdx.x * 64;
  int nbase = blockIdx.y * 1536;
  int dg = t & 15, cg = t >> 4;
  float acc[4][4];
  #pragma unroll
  for (int i=0;i<4;++i){
    #pragma unroll
    for (int j=0;j<4;++j) acc[i][j]=0.f;
  }
  for (int n0 = 0; n0 < 1536; n0 += 64){
    __syncthreads();
    #pragma unroll
    for (int i = 0; i < 4; ++i){
      int fidx = t + 256*i;
      int r = fidx >> 4;
      int dc = (fidx & 15) * 4;
      int n = nbase + n0 + r;
      const float* rp = (n < NSUP) ? (sup + (size_t)n*DDIM)
                                   : (feats + (size_t)(n-NSUP)*DDIM);
      *(float4*)&ssx[r*68 + dc] = *(const float4*)(rp + d0 + dc);
    }
    #pragma unroll
    for (int i = 0; i < 4; ++i){
      int fidx = t + 256*i;
      int r = fidx >> 4;
      int cc = (fidx & 15) * 4;
      int n = nbase + n0 + r;
      float sc = snm[n];
      float4 v;
      if (n < NSUP){
        float4 lb = *(const float4*)(labels + (size_t)n*CCLS + cc);
        v.x = lb.x*sc; v.y = lb.y*sc; v.z = lb.z*sc; v.w = lb.w*sc;
      } else {
        int b = n - NSUP;
        float base = w_c[b] * sc;
        int p = pred[b];
        v.x = (p == cc+0) ? base : 0.f;
        v.y = (p == cc+1) ? base : 0.f;
        v.z = (p == cc+2) ? base : 0.f;
        v.w = (p == cc+3) ? base : 0.f;
      }
      *(float4*)&sl[r*68 + cc] = v;
    }
    __syncthreads();
    #pragma unroll 4
    for (int kk = 0; kk < 64; ++kk){
      float4 a = *(float4*)&ssx[kk*68 + 4*dg];
      float4 b = *(float4*)&sl[kk*68 + 4*cg];
      float av[4] = {a.x,a.y,a.z,a.w};
      float bv[4] = {b.x,b.y,b.z,b.w};
      #pragma unroll
      for (int i=0;i<4;++i){
        #pragma unroll
        for (int j=0;j<4;++j) acc[i][j] = fmaf(av[i], bv[j], acc[i][j]);
      }
    }
  }
  #pragma unroll
  for (int i=0;i<4;++i){
    #pragma unroll
    for (int j=0;j<4;++j)
      atomicAdd(&protos_un[(size_t)(d0 + 4*dg + i)*CCLS + 4*cg + j], acc[i][j]);
  }
}

// ---------------- 10. protos normalize ----------------
__global__ __launch_bounds__(256)
void k_protos_norm(const float* __restrict__ protos_un, const float* __restrict__ colsum,
                   float* __restrict__ protos_t){
  int c = blockIdx.x, t = threadIdx.x;
  __shared__ float sh4[4];
  float cs = fmaxf(colsum[c], FEPS);
  float v[4];
  float ss = 0.f;
  #pragma unroll
  for (int i=0;i<4;++i){
    int d = t + 256*i;
    v[i] = protos_un[(size_t)d*CCLS + c] / cs;
    ss += v[i]*v[i];
  }
  ss = blockSum256(ss, sh4);
  float inv = 1.0f / fmaxf(sqrtf(ss), FEPS);
  #pragma unroll
  for (int i=0;i<4;++i){
    int d = t + 256*i;
    protos_t[(size_t)c*DDIM + d] = v[i]*inv;
  }
}

// ---------------- 11. loss2 ----------------
__global__ __launch_bounds__(256)
void k_loss2(const float* __restrict__ feats, const float* __restrict__ protos_t,
             const int* __restrict__ pred, const float* __restrict__ w_c,
             const float* __restrict__ fnorm, float* __restrict__ scal){
  int row = blockIdx.x, t = threadIdx.x;
  float wc = w_c[row];
  if (wc == 0.f) return;
  __shared__ __align__(16) float f[DDIM];
  __shared__ float z[CCLS];
  float inv = 1.0f / fmaxf(fnorm[row], FEPS);
  { float4 v = ((const float4*)(feats + (size_t)row*DDIM))[t];
    v.x*=inv; v.y*=inv; v.z*=inv; v.w*=inv;
    ((float4*)f)[t] = v; }
  __syncthreads();
  int w = t >> 6, lane = t & 63;
  for (int ci=0; ci<16; ++ci){
    int c = w*16+ci;
    const float4* pc = (const float4*)(protos_t + (size_t)c*DDIM);
    float d = 0.f;
    #pragma unroll
    for (int j=0;j<4;++j){
      float4 a = pc[lane + 64*j];
      float4 b = ((float4*)f)[lane + 64*j];
      d += a.x*b.x+a.y*b.y+a.z*b.z+a.w*b.w;
    }
    d = waveSum(d);
    if (lane==0) z[c] = d;
  }
  __syncthreads();
  if (w == 0){
    float zz = z[lane];
    float m = waveMax(zz);
    float sv = waveSum(expf(zz - m));
    if (lane == 0){
      float lse = m + logf(sv);
      float ce = lse - z[pred[row]];
      atomicAdd(&scal[SC_L2NUM], ce * wc);
    }
  }
}

// ---------------- 12. sim stage-1 (best-measured config): f16-hi single-pass
//   MFMA, 256x256 tile, 16 waves (4x4), gload_lds dbuf from K-tiled
//   pre-swizzled operands (contiguous 1KB segments), per-chunk top-6 ----------------
__global__ __launch_bounds__(1024, 1)
void k_sim_approx(const _Float16* __restrict__ ht, const float* __restrict__ snm,
                  float* __restrict__ cval, int* __restrict__ cidx){
  __shared__ __align__(16) _Float16 lds[2*16384];   // 64KB
  __shared__ float sns[256];
  int t = threadIdx.x;
  int w = t >> 6, lane = t & 63;
  int wr = w >> 2, wcn = w & 3;
  int l31 = lane & 31, hi = lane >> 5;
  int bidl = blockIdx.y * 48 + blockIdx.x;
  int xcd = bidl & 7, lin = bidl >> 3;
  int yb = xcd * 2 + (lin / 48);
  int xb = lin - (lin / 48) * 48;
  int m0 = xb * 256, n0 = yb * 256;
  if (t < 256) sns[t] = snm[m0 + t];
  const _Float16* Abase = ht + (size_t)(m0 + w*16)*32 + (size_t)lane*8;
  const _Float16* Bbase = ht + (size_t)(NSUP + n0 + w*16)*32 + (size_t)lane*8;
  f32x16 acc[2][2];
  #pragma unroll
  for (int i=0;i<2;++i){
    #pragma unroll
    for (int j=0;j<2;++j) acc[i][j] = (f32x16)(0.f);
  }

  #define SIM_ST(b, kt) do {                                                      \
    __builtin_amdgcn_global_load_lds(                                             \
      (const __attribute__((address_space(1))) void*)(Abase + (size_t)(kt)*(NTOT*32)),\
      (__attribute__((address_space(3))) void*)(lds + (b)*16384 + w*512), 16,0,0);\
    __builtin_amdgcn_global_load_lds(                                             \
      (const __attribute__((address_space(1))) void*)(Bbase + (size_t)(kt)*(NTOT*32)),\
      (__attribute__((address_space(3))) void*)(lds + (b)*16384 + 8192 + w*512), 16,0,0);\
  } while(0)

  SIM_ST(0, 0);
  for (int kt = 0; kt < 32; ++kt){
    const _Float16* buf = lds + (kt&1)*16384;
    __syncthreads();                      // drains vmcnt: tile kt landed (all waves)
    half8_t af[2][2], bf[2][2];
    #pragma unroll
    for (int p=0;p<2;++p){
      int Ra = wr*64 + p*32 + l31;
      int sw = (Ra>>3)&3;
      #pragma unroll
      for (int kf=0;kf<2;++kf)
        af[p][kf] = *(const half8_t*)(buf + Ra*32 + (((kf*2+hi)^sw))*8);
    }
    #pragma unroll
    for (int ni=0;ni<2;++ni){
      int Rb = wcn*64 + ni*32 + l31;
      int sw = (Rb>>3)&3;
      #pragma unroll
      for (int kf=0;kf<2;++kf)
        bf[ni][kf] = *(const half8_t*)(buf + 8192 + Rb*32 + (((kf*2+hi)^sw))*8);
    }
    if (kt < 31) SIM_ST((kt+1)&1, kt+1);  // issue-early; lands during MFMA + next wait
    __builtin_amdgcn_s_setprio(1);
    #pragma unroll
    for (int p=0;p<2;++p){
      #pragma unroll
      for (int ni=0;ni<2;++ni){
        #pragma unroll
        for (int kf=0;kf<2;++kf)
          acc[p][ni] = __builtin_amdgcn_mfma_f32_32x32x16_f16(af[p][kf], bf[ni][kf], acc[p][ni], 0,0,0);
      }
    }
    __builtin_amdgcn_s_setprio(0);
  }
  #undef SIM_ST
  // ---- epilogue: mask+scale (order-preserving per col), per-chunk top-6 ----
  // C layout (32x32): col = lane&31, row = (reg&3) + 8*(reg>>2) + 4*(lane>>5)
  __syncthreads();
  float tv[2][6]; int ti[2][6];
  #pragma unroll
  for (int ni=0;ni<2;++ni){
    #pragma unroll
    for (int k=0;k<6;++k){ tv[ni][k] = -INFINITY; ti[ni][k] = 0x7fffffff; }
  }
  #pragma unroll
  for (int ni=0;ni<2;++ni){
    #pragma unroll
    for (int p=0;p<2;++p){
      #pragma unroll
      for (int r=0;r<16;++r){
        int rl = wr*64 + p*32 + (r&3) + 8*(r>>2) + 4*hi;
        float sn = sns[rl];
        float v = acc[p][ni][r] * fabsf(sn);
        v = (sn > 0.f) ? v : -INFINITY;
        top6_insert(tv[ni], ti[ni], v, m0 + rl);
      }
    }
  }
  // merge lane^32 (same col, other hi)
  #pragma unroll
  for (int ni=0;ni<2;++ni){
    float pv[6]; int pi[6];
    #pragma unroll
    for (int k=0;k<6;++k){ pv[k] = __shfl_xor(tv[ni][k], 32); pi[k] = __shfl_xor(ti[ni][k], 32); }
    #pragma unroll
    for (int k=0;k<6;++k) top6_insert(tv[ni], ti[ni], pv[k], pi[k]);
  }
  // cross-wr merge via LDS: [256 cols][stride 25], slots wr*6+k (24 used + 1 pad)
  float* MV = (float*)lds;
  int*   MI = (int*)lds + 6400;
  if (hi == 0){
    #pragma unroll
    for (int ni=0;ni<2;++ni){
      int col = wcn*64 + ni*32 + l31;
      #pragma unroll
      for (int k=0;k<6;++k){
        MV[col*25 + wr*6 + k] = tv[ni][k];
        MI[col*25 + wr*6 + k] = ti[ni][k];
      }
    }
  }
  __syncthreads();
  if (t < 256){
    float bv[6]; int bi[6];
    #pragma unroll
    for (int k=0;k<6;++k){ bv[k] = -INFINITY; bi[k] = 0x7fffffff; }
    for (int j = 0; j < 24; ++j) top6_insert(bv, bi, MV[t*25 + j], MI[t*25 + j]);
    float* co = cval + (size_t)(n0 + t)*KCAND + xb*6;
    int*   ci = cidx + (size_t)(n0 + t)*KCAND + xb*6;
    #pragma unroll
    for (int k=0;k<6;++k){ co[k] = bv[k]; ci[k] = bi[k]; }
  }
}

// ---------------- 13. stage-2: approx top-10 -> exact fp32 rescore -> top-5 -> NCL ----------------
__global__ __launch_bounds__(256)
void k_rescore_ncl(const float* __restrict__ cval, const int* __restrict__ cidx,
                   const float* __restrict__ sup, const float* __restrict__ feats,
                   const float* __restrict__ rb, const float* __restrict__ snm,
                   const float* __restrict__ scores_old, const float* __restrict__ probs,
                   const float* __restrict__ logp, const float* __restrict__ w_c,
                   float* __restrict__ scal){
  int t = threadIdx.x, w = t >> 6, lane = t & 63;
  int b = blockIdx.x*4 + w;
  // load candidates (KCAND=288 -> 5 per lane, last partial)
  float lv[5]; int li[5];
  #pragma unroll
  for (int j=0;j<5;++j){
    int idx = lane + 64*j;
    bool ok = idx < KCAND;
    lv[j] = ok ? cval[(size_t)b*KCAND + idx] : -INFINITY;
    li[j] = ok ? cidx[(size_t)b*KCAND + idx] : 0x7fffffff;
  }
  // per-lane sort descending (5 elems)
  #pragma unroll
  for (int a=0;a<4;++a){
    #pragma unroll
    for (int c=0;c<4-a;++c){
      bool sw = lv[c+1] > lv[c];
      float fv = sw ? lv[c+1] : lv[c];  float fw = sw ? lv[c] : lv[c+1];
      int   iv = sw ? li[c+1] : li[c];  int   iw = sw ? li[c] : li[c+1];
      lv[c]=fv; lv[c+1]=fw; li[c]=iv; li[c+1]=iw;
    }
  }
  // extract global approx top-10
  float t10v[10]; int t10i[10];
  int head = 0;
  #pragma unroll
  for (int k=0;k<10;++k){
    float hv = -INFINITY; int hidx = 0x7fffffff;
    switch(head){
      case 0: hv=lv[0]; hidx=li[0]; break;
      case 1: hv=lv[1]; hidx=li[1]; break;
      case 2: hv=lv[2]; hidx=li[2]; break;
      case 3: hv=lv[3]; hidx=li[3]; break;
      case 4: hv=lv[4]; hidx=li[4]; break;
      default: break;
    }
    float m = waveMax(hv);
    unsigned long long bal = __ballot(hv == m);
    int wl = __ffsll(bal) - 1;
    t10v[k] = m;
    t10i[k] = __shfl(hidx, wl);
    if (lane == wl) head++;
  }
  (void)t10v;
  // exact fp32 rescore of the 10
  float4 fr0 = *(const float4*)(feats + (size_t)b*DDIM + lane*16);
  float4 fr1 = *(const float4*)(feats + (size_t)b*DDIM + lane*16 + 4);
  float4 fr2 = *(const float4*)(feats + (size_t)b*DDIM + lane*16 + 8);
  float4 fr3 = *(const float4*)(feats + (size_t)b*DDIM + lane*16 + 12);
  float rbv = rb[b];
  float ev[10];
  #pragma unroll
  for (int c=0;c<10;++c){
    int idx = t10i[c];
    const float* srow = (idx < NSUP) ? (sup + (size_t)idx*DDIM)
                                     : (feats + (size_t)(idx-NSUP)*DDIM);
    float4 s0 = *(const float4*)(srow + lane*16);
    float4 s1 = *(const float4*)(srow + lane*16 + 4);
    float4 s2 = *(const float4*)(srow + lane*16 + 8);
    float4 s3 = *(const float4*)(srow + lane*16 + 12);
    float d = fr0.x*s0.x + fr0.y*s0.y + fr0.z*s0.z + fr0.w*s0.w
            + fr1.x*s1.x + fr1.y*s1.y + fr1.z*s1.z + fr1.w*s1.w
            + fr2.x*s2.x + fr2.y*s2.y + fr2.z*s2.z + fr2.w*s2.w
            + fr3.x*s3.x + fr3.y*s3.y + fr3.z*s3.z + fr3.w*s3.w;
    d = waveSum(d);
    ev[c] = d * rbv * fabsf(snm[idx]);
  }
  // select top-5 exact with reference tie-break (value desc, then index asc)
  int used = 0;
  int sel[5];
  #pragma unroll
  for (int k=0;k<5;++k){
    float bb = -INFINITY; int bbi = 0x7fffffff; int bj = 0;
    #pragma unroll
    for (int j=0;j<10;++j){
      bool free_ = !((used >> j) & 1);
      bool better = free_ && ((ev[j] > bb) || (ev[j] == bb && t10i[j] < bbi));
      bb  = better ? ev[j]   : bb;
      bbi = better ? t10i[j] : bbi;
      bj  = better ? j       : bj;
    }
    used |= (1 << bj);
    sel[k] = bbi;
  }
  // NCL
  float tg = 0.f;
  #pragma unroll
  for (int k=0;k<5;++k){
    int ix = sel[k];
    const float* srow = (ix < NSUP) ? (scores_old + (size_t)ix*CCLS)
                                    : (probs + (size_t)(ix-NSUP)*CCLS);
    tg += srow[lane];
  }
  tg *= 0.2f;
  float d = tg * logp[(size_t)b*CCLS + lane];
  d = waveSum(d);
  if (lane == 0) atomicAdd(&scal[SC_L3NUM], -d * (1.0f - w_c[b]));
}

// ---------------- 14. final combine ----------------
__global__ void k_final(const float* __restrict__ pm_acc, const float* __restrict__ scal,
                        float* __restrict__ out){
  int lane = threadIdx.x;  // 64 threads
  float pm = pm_acc[lane] * (1.0f/BBATCH);
  float dterm = pm * logf(pm + FEPS);
  float dv = waveSum(dterm);
  if (lane == 0){
    float div = -dv;
    float tsallis = scal[SC_TSAL] * (1.0f/BBATCH);
    float swc = scal[SC_SUMWC];
    float l1 = tsallis - div;
    float l2 = scal[SC_L2NUM] / fmaxf(swc, 1.0f);
    float l3 = scal[SC_L3NUM] / fmaxf((float)BBATCH - swc, 1.0f);
    out[0] = l1 + l2 + l3;
  }
}

// ---------------- launch ----------------
extern "C" void kernel_launch(void* const* d_in, const int* in_sizes, int n_in,
                              void* d_out, int out_size, void* d_ws, size_t ws_size,
                              hipStream_t stream){
  (void)in_sizes; (void)n_in; (void)out_size; (void)ws_size;
  const float* x      = (const float*)d_in[0];
  // d_in[1] = y (unused by the reference loss)
  const float* Wf     = (const float*)d_in[2];
  const float* Wc     = (const float*)d_in[3];
  const float* bc     = (const float*)d_in[4];
  const float* sup    = (const float*)d_in[5];
  const float* labels = (const float*)d_in[6];
  const float* scores = (const float*)d_in[7];
  float* ws = (float*)d_ws;

  float* feats  = ws + OFF_FEATS;
  float* featp1 = ws + OFF_FEATP1;
  unsigned short* wfth = (unsigned short*)(ws + OFF_WFTH);
  unsigned short* wftl = (unsigned short*)(ws + OFF_WFTL);
  _Float16* ht  = (_Float16*)(ws + OFF_HT);
  float* probs  = ws + OFF_PROBS;
  float* logp   = ws + OFF_LOGP;
  float* fnorm  = ws + OFF_FNORM;
  float* snorm  = ws + OFF_SNORM;
  float* pmax   = ws + OFF_PMAX;
  float* e_row  = ws + OFF_EROW;
  float* w_c    = ws + OFF_WC;
  int*   pred   = (int*)(ws + OFF_PRED);
  float* rb     = ws + OFF_RB;
  float* snm    = ws + OFF_SNM;
  float* protot = ws + OFF_PROTOT;
  float* cvalp  = ws + OFF_CVAL;
  int*   cidxp  = (int*)(ws + OFF_CIDX);
  float* m_acc  = ws + OFF_MACC;
  float* pm_acc = ws + OFF_PMACC;
  float* colsum = ws + OFF_COLS;
  float* scal   = ws + OFF_SCAL;
  float* protun = ws + OFF_PROTUN;

  hipMemsetAsync(ws + OFF_ZERO, 0, (OFF_ZEND - OFF_ZERO)*sizeof(float), stream);

  k_entropy      <<<BBATCH, 256, 0, stream>>>(x, e_row, scal);
  k_wft          <<<dim3(DDIM/64, LLEN/64), 256, 0, stream>>>(Wf, wfth, wftl);
  k_feats_mfma   <<<dim3(8, 32, 2), 256, 0, stream>>>(x, wfth, wftl, feats);
  k_supnorm      <<<NSUP/4, 256, 0, stream>>>(sup, snorm, ht);
  k_logits       <<<BBATCH, 256, 0, stream>>>(feats, featp1, Wc, bc, probs, logp, pmax, pred, fnorm, scal, ht);
  k_mask         <<<32, 256, 0, stream>>>(e_row, pmax, fnorm, snorm, pred, w_c, rb, snm, colsum, scal);
  k_colsum_labels<<<32, 256, 0, stream>>>(labels, colsum);
  k_m_accum      <<<64, 256, 0, stream>>>(probs, w_c, m_acc);
  k_loss1        <<<64, 256, 0, stream>>>(probs, m_acc, pm_acc, scal);
  k_protos_gemm  <<<dim3(16, 8), 256, 0, stream>>>(sup, feats, labels, pred, w_c, snm, protun);
  k_protos_norm  <<<CCLS, 256, 0, stream>>>(protun, colsum, protot);
  k_loss2        <<<BBATCH, 256, 0, stream>>>(feats, protot, pred, w_c, fnorm, scal);
  k_sim_approx   <<<dim3(48, 16), 1024, 0, stream>>>(ht, snm, cvalp, cidxp);
  k_rescore_ncl  <<<BBATCH/4, 256, 0, stream>>>(cvalp, cidxp, sup, feats, rb, snm, scores, probs, logp, w_c, scal);
  k_final        <<<1, 64, 0, stream>>>(pm_acc, scal, (float*)d_out);
}